// Round 1
// baseline (468.730 us; speedup 1.0000x reference)
//
#include <hip/hip_runtime.h>

#define NPTS 8192
#define NSLICE 16
#define SLICE_LEN (NPTS / NSLICE)
#define KNN 8

// ---------------------------------------------------------------------------
// KNN stage 1: each block handles 256 queries x one slice of 512 candidates.
// Distance formula replicates numpy bit-for-bit as closely as possible:
//   x2 = ((x*x + y*y) + z*z)        (separate roundings, numpy square+sum)
//   dot = fma(z,z2, fma(y,y2, x*x2)) (BLAS-style FMA chain)
//   d   = (x2i + x2j) + (-2*dot)     (two roundings, matches A - 2*B)
// ---------------------------------------------------------------------------
__global__ __launch_bounds__(256) void knn_partial_kernel(
    const float* __restrict__ pts, float* __restrict__ part_d,
    int* __restrict__ part_i) {
  __shared__ float4 sp[SLICE_LEN];
  const int t = threadIdx.x;
  const int q = blockIdx.x * 256 + t;
  const int jbase = blockIdx.y * SLICE_LEN;
  for (int p = t; p < SLICE_LEN; p += 256) {
    float x = pts[(jbase + p) * 3 + 0];
    float y = pts[(jbase + p) * 3 + 1];
    float z = pts[(jbase + p) * 3 + 2];
    float x2 = __fadd_rn(__fadd_rn(__fmul_rn(x, x), __fmul_rn(y, y)),
                         __fmul_rn(z, z));
    sp[p] = make_float4(x, y, z, x2);
  }
  __syncthreads();
  const float qx = pts[q * 3 + 0], qy = pts[q * 3 + 1], qz = pts[q * 3 + 2];
  const float q2 = __fadd_rn(
      __fadd_rn(__fmul_rn(qx, qx), __fmul_rn(qy, qy)), __fmul_rn(qz, qz));
  float bd[KNN];
  int bi[KNN];
#pragma unroll
  for (int s = 0; s < KNN; ++s) { bd[s] = 3.4e38f; bi[s] = 0; }
  for (int p = 0; p < SLICE_LEN; ++p) {
    float4 pj = sp[p];
    float dot = __fmaf_rn(qz, pj.z, __fmaf_rn(qy, pj.y, __fmul_rn(qx, pj.x)));
    float t1 = __fadd_rn(q2, pj.w);
    float d = __fadd_rn(t1, __fmul_rn(-2.0f, dot));
    if (d < bd[KNN - 1]) {  // strict <: ties keep earlier (lower j) candidate
      float cd = d;
      int ci = jbase + p;
#pragma unroll
      for (int s = 0; s < KNN; ++s) {
        if (cd < bd[s]) {
          float td = bd[s]; int ti = bi[s];
          bd[s] = cd; bi[s] = ci; cd = td; ci = ti;
        }
      }
    }
  }
#pragma unroll
  for (int s = 0; s < KNN; ++s) {
    part_d[(blockIdx.y * KNN + s) * NPTS + q] = bd[s];
    part_i[(blockIdx.y * KNN + s) * NPTS + q] = bi[s];
  }
}

// KNN stage 2: merge 16 slices x 8 candidates per query (slice order ==
// ascending-j order, so strict < keeps the lower index on ties).
__global__ __launch_bounds__(256) void knn_merge_kernel(
    const float* __restrict__ part_d, const int* __restrict__ part_i,
    int* __restrict__ nbr) {
  const int q = blockIdx.x * 256 + threadIdx.x;
  float bd[KNN];
  int bi[KNN];
#pragma unroll
  for (int s = 0; s < KNN; ++s) { bd[s] = 3.4e38f; bi[s] = 0; }
  for (int sl = 0; sl < NSLICE; ++sl) {
#pragma unroll
    for (int e = 0; e < KNN; ++e) {
      float d = part_d[(sl * KNN + e) * NPTS + q];
      int ci0 = part_i[(sl * KNN + e) * NPTS + q];
      if (d < bd[KNN - 1]) {
        float cd = d;
        int ci = ci0;
#pragma unroll
        for (int s = 0; s < KNN; ++s) {
          if (cd < bd[s]) {
            float td = bd[s]; int ti = bi[s];
            bd[s] = cd; bi[s] = ci; cd = td; ci = ti;
          }
        }
      }
    }
  }
#pragma unroll
  for (int s = 0; s < KNN; ++s) nbr[q * KNN + s] = bi[s];
}

// Per-edge first layer of EdgeConv1: H1[edge][m] = relu(e @ W1 + b1), m<64.
// edge = i*8+e, e = [x_i, x_j - x_i] (6 dims).
__global__ __launch_bounds__(256) void h1_edges_kernel(
    const float* __restrict__ pts, const int* __restrict__ nbr,
    const float* __restrict__ W1, const float* __restrict__ b1,
    float* __restrict__ H1) {
  const int id = blockIdx.x * 256 + threadIdx.x;  // 65536 * 16
  const int te = id >> 4, mq = id & 15;
  const int i = te >> 3;
  const int j = nbr[te];
  const float xi0 = pts[i * 3], xi1 = pts[i * 3 + 1], xi2 = pts[i * 3 + 2];
  const float d0 = pts[j * 3] - xi0, d1 = pts[j * 3 + 1] - xi1,
              d2 = pts[j * 3 + 2] - xi2;
  const int m = mq * 4;
  float4 o;
  float* oa = (float*)&o;
#pragma unroll
  for (int d = 0; d < 4; ++d) {
    int c = m + d;
    float v = b1[c];
    v += xi0 * W1[0 * 64 + c] + xi1 * W1[1 * 64 + c] + xi2 * W1[2 * 64 + c];
    v += d0 * W1[3 * 64 + c] + d1 * W1[4 * 64 + c] + d2 * W1[5 * 64 + c];
    oa[d] = fmaxf(v, 0.0f);
  }
  *(float4*)&H1[(size_t)te * 64 + m] = o;
}

// Build Wcat (128 x 256): cols 0..127 = W3[0:128,:] (xi part),
// cols 128..255 = W3[128:256,:] (xj-xi part). W3 is (256,128) row-major.
__global__ __launch_bounds__(256) void build_wcat_kernel(
    const float* __restrict__ W3, float* __restrict__ Wcat) {
  const int id = blockIdx.x * 256 + threadIdx.x;  // 32768
  const int k = id >> 8, c = id & 255;
  Wcat[id] = (c < 128) ? W3[k * 128 + c] : W3[(128 + k) * 128 + (c - 128)];
}

// Per-edge first layer of EdgeConv2: H2[edge][c] = relu(A_i + C_j - C_i),
// where AC[p][0:128] = A_p (includes b3), AC[p][128:256] = C_p.
__global__ __launch_bounds__(256) void h2_edges_kernel(
    const float* __restrict__ AC, const int* __restrict__ nbr,
    float* __restrict__ H2) {
  const int id = blockIdx.x * 256 + threadIdx.x;  // 65536 * 32
  const int te = id >> 5, cq = id & 31;
  const int i = te >> 3;
  const int j = nbr[te];
  const int c = cq * 4;
  float4 a = *(const float4*)&AC[(size_t)i * 256 + c];
  float4 ci = *(const float4*)&AC[(size_t)i * 256 + 128 + c];
  float4 cj = *(const float4*)&AC[(size_t)j * 256 + 128 + c];
  float4 h;
  h.x = fmaxf(a.x + cj.x - ci.x, 0.0f);
  h.y = fmaxf(a.y + cj.y - ci.y, 0.0f);
  h.z = fmaxf(a.z + cj.z - ci.z, 0.0f);
  h.w = fmaxf(a.w + cj.w - ci.w, 0.0f);
  *(float4*)&H2[(size_t)te * 128 + c] = h;
}

// ---------------------------------------------------------------------------
// Tiled fp32 GEMM: out = op(A[M x K] @ B[K x Nglob] + bias).
// 64x64 tile, K-panel 64 in LDS, 4x4 register micro-tile per thread.
// SEGMAX: max over groups of 8 consecutive A-rows (edges of one point),
//         then +bias (and relu if RELU) -> out has M/8 rows.
// Bias applied only for global col < bias_limit.
// ---------------------------------------------------------------------------
template <bool SEGMAX, bool RELU>
__global__ __launch_bounds__(256) void gemm_kernel(
    const float* __restrict__ A, const float* __restrict__ B,
    const float* __restrict__ bias, int bias_limit, float* __restrict__ out,
    int K, int Nglob) {
  __shared__ float As[64][64];  // As[k][row]  (A-panel transposed)
  __shared__ float Bs[64][64];  // Bs[k][col]
  const int t = threadIdx.x;
  const int tx = t & 15, ty = t >> 4;
  const int rowBase = blockIdx.y * 64;
  const int colBase = blockIdx.x * 64;
  const float4* A4 = (const float4*)A;
  float acc[4][4] = {};

  for (int k0 = 0; k0 < K; k0 += 64) {
    // stage A panel (64 rows x 64 k), transposed into As[k][row]
#pragma unroll
    for (int it = 0; it < 4; ++it) {
      int idx = it * 256 + t;
      int row = idx & 63, kq = idx >> 6;  // kq in 0..15
      float4 av = A4[(size_t)(rowBase + row) * (K >> 2) + (k0 >> 2) + kq];
      As[kq * 4 + 0][row] = av.x;
      As[kq * 4 + 1][row] = av.y;
      As[kq * 4 + 2][row] = av.z;
      As[kq * 4 + 3][row] = av.w;
    }
    // stage B panel (64 k x 64 cols)
#pragma unroll
    for (int it = 0; it < 4; ++it) {
      int idx = it * 256 + t;
      int cq = idx & 15, kr = idx >> 4;  // kr in 0..63
      float4 bv = *(const float4*)&B[(size_t)(k0 + kr) * Nglob + colBase + cq * 4];
      *(float4*)&Bs[kr][cq * 4] = bv;
    }
    __syncthreads();
#pragma unroll 8
    for (int k = 0; k < 64; ++k) {
      float4 a = *(const float4*)&As[k][ty * 4];
      float4 b = *(const float4*)&Bs[k][tx * 4];
      const float ar[4] = {a.x, a.y, a.z, a.w};
      const float br[4] = {b.x, b.y, b.z, b.w};
#pragma unroll
      for (int i = 0; i < 4; ++i)
#pragma unroll
        for (int jj = 0; jj < 4; ++jj)
          acc[i][jj] = fmaf(ar[i], br[jj], acc[i][jj]);
    }
    __syncthreads();
  }

  if (SEGMAX) {
    float* Mx = &As[0][0];  // reuse As as 16x64 partial-max buffer
#pragma unroll
    for (int jj = 0; jj < 4; ++jj) {
      float m = fmaxf(fmaxf(acc[0][jj], acc[1][jj]),
                      fmaxf(acc[2][jj], acc[3][jj]));
      Mx[ty * 64 + tx * 4 + jj] = m;
    }
    __syncthreads();
    if (t < 128) {
      int p = t >> 4, cq = t & 15;
      int c = cq * 4;
      float4 o;
      float* oa = (float*)&o;
#pragma unroll
      for (int jj = 0; jj < 4; ++jj) {
        float v = fmaxf(Mx[(2 * p) * 64 + c + jj], Mx[(2 * p + 1) * 64 + c + jj]);
        int cg = colBase + c + jj;
        if (cg < bias_limit) v += bias[cg];
        if (RELU) v = fmaxf(v, 0.0f);
        oa[jj] = v;
      }
      *(float4*)&out[(size_t)(blockIdx.y * 8 + p) * Nglob + colBase + c] = o;
    }
  } else {
#pragma unroll
    for (int i = 0; i < 4; ++i) {
      float4 o;
      float* oa = (float*)&o;
#pragma unroll
      for (int jj = 0; jj < 4; ++jj) {
        float v = acc[i][jj];
        int cg = colBase + tx * 4 + jj;
        if (cg < bias_limit) v += bias[cg];
        oa[jj] = v;
      }
      *(float4*)&out[(size_t)(rowBase + ty * 4 + i) * Nglob + colBase + tx * 4] = o;
    }
  }
}

extern "C" void kernel_launch(void* const* d_in, const int* in_sizes, int n_in,
                              void* d_out, int out_size, void* d_ws,
                              size_t ws_size, hipStream_t stream) {
  const float* pts = (const float*)d_in[0];  // (2,4096,3) -> (8192,3)
  const float* W1 = (const float*)d_in[1];   // (6,64)
  const float* b1 = (const float*)d_in[2];   // (64)
  const float* W2 = (const float*)d_in[3];   // (64,128)
  const float* b2 = (const float*)d_in[4];   // (128)
  const float* W3 = (const float*)d_in[5];   // (256,128)
  const float* b3 = (const float*)d_in[6];   // (128)
  const float* W4 = (const float*)d_in[7];   // (128,256)
  const float* b4 = (const float*)d_in[8];   // (256)
  float* out = (float*)d_out;                // (8192,256)

  float* w = (float*)d_ws;
  float* part_d = w;                               // 16*8*8192 = 1048576 f
  int* part_i = (int*)(w + 1048576);               // 1048576 i
  int* nbr = (int*)(w + 2097152);                  // 65536 i
  float* H1 = w + 2162688;                         // 65536*64 = 4194304 f
  float* y = w + 6356992;                          // 8192*128 = 1048576 f
  float* Wcat = w + 7405568;                       // 128*256 = 32768 f
  float* AC = w + 7438336;                         // 8192*256 = 2097152 f
  float* H2 = w + 9535488;                         // 65536*128 = 8388608 f
  // total 17924096 floats = ~71.7 MB of workspace

  // 1. KNN
  knn_partial_kernel<<<dim3(32, NSLICE), 256, 0, stream>>>(pts, part_d, part_i);
  knn_merge_kernel<<<32, 256, 0, stream>>>(part_d, part_i, nbr);

  // 2. EdgeConv1: H1 then GEMM(H1 @ W2) + max8 + b2 + relu -> y
  h1_edges_kernel<<<4096, 256, 0, stream>>>(pts, nbr, W1, b1, H1);
  gemm_kernel<true, true><<<dim3(2, 1024), 256, 0, stream>>>(
      H1, W2, b2, 128, y, 64, 128);

  // 3. EdgeConv2: AC = y @ Wcat (+b3 on first half), H2, GEMM + max8 + b4
  build_wcat_kernel<<<128, 256, 0, stream>>>(W3, Wcat);
  gemm_kernel<false, false><<<dim3(4, 128), 256, 0, stream>>>(
      y, Wcat, b3, 128, AC, 128, 256);
  h2_edges_kernel<<<8192, 256, 0, stream>>>(AC, nbr, H2);
  gemm_kernel<true, false><<<dim3(4, 1024), 256, 0, stream>>>(
      H2, W4, b4, 256, out, 128, 256);
}

// Round 2
// 275.869 us; speedup vs baseline: 1.6991x; 1.6991x over previous
//
#include <hip/hip_runtime.h>

#define NPTS 8192
#define NSLICE 16
#define SLICE_LEN (NPTS / NSLICE)
#define KNN 8

// Branch-free insert of (dist,idx) into ascending sorted regs d0..d7/i0..i7.
// c_s = dist<d_s is monotone in s; new d_s = c_s ? (c_{s-1} ? d_{s-1} : dist) : d_s.
// All flags computed from OLD values, then in-place descending update.
#define TOPK_INSERT(dist, idx)                                              \
  {                                                                         \
    const float _d = (dist);                                                \
    const int _ix = (idx);                                                  \
    const bool c0 = _d < d0, c1 = _d < d1, c2 = _d < d2, c3 = _d < d3;      \
    const bool c4 = _d < d4, c5 = _d < d5, c6 = _d < d6, c7 = _d < d7;      \
    d7 = c7 ? (c6 ? d6 : _d) : d7; i7 = c7 ? (c6 ? i6 : _ix) : i7;          \
    d6 = c6 ? (c5 ? d5 : _d) : d6; i6 = c6 ? (c5 ? i5 : _ix) : i6;          \
    d5 = c5 ? (c4 ? d4 : _d) : d5; i5 = c5 ? (c4 ? i4 : _ix) : i5;          \
    d4 = c4 ? (c3 ? d3 : _d) : d4; i4 = c4 ? (c3 ? i3 : _ix) : i4;          \
    d3 = c3 ? (c2 ? d2 : _d) : d3; i3 = c3 ? (c2 ? i2 : _ix) : i3;          \
    d2 = c2 ? (c1 ? d1 : _d) : d2; i2 = c2 ? (c1 ? i1 : _ix) : i2;          \
    d1 = c1 ? (c0 ? d0 : _d) : d1; i1 = c1 ? (c0 ? i0 : _ix) : i1;          \
    d0 = c0 ? _d : d0;             i0 = c0 ? _ix : i0;                      \
  }

#define TOPK_DECL                                                           \
  float d0 = 3.4e38f, d1 = 3.4e38f, d2 = 3.4e38f, d3 = 3.4e38f,            \
        d4 = 3.4e38f, d5 = 3.4e38f, d6 = 3.4e38f, d7 = 3.4e38f;            \
  int i0 = 0, i1 = 0, i2 = 0, i3 = 0, i4 = 0, i5 = 0, i6 = 0, i7 = 0;

// ---------------------------------------------------------------------------
// KNN stage 1: 256 queries x one slice of 512 candidates per block.
// Distance replicates numpy rounding:
//   x2 = ((x*x + y*y) + z*z); dot = fma-chain; d = (x2i + x2j) + (-2*dot)
// ---------------------------------------------------------------------------
__global__ __launch_bounds__(256) void knn_partial_kernel(
    const float* __restrict__ pts, float* __restrict__ part_d,
    int* __restrict__ part_i) {
  __shared__ float4 sp[SLICE_LEN];
  const int t = threadIdx.x;
  const int q = blockIdx.x * 256 + t;
  const int jbase = blockIdx.y * SLICE_LEN;
  for (int p = t; p < SLICE_LEN; p += 256) {
    float x = pts[(jbase + p) * 3 + 0];
    float y = pts[(jbase + p) * 3 + 1];
    float z = pts[(jbase + p) * 3 + 2];
    float x2 = __fadd_rn(__fadd_rn(__fmul_rn(x, x), __fmul_rn(y, y)),
                         __fmul_rn(z, z));
    sp[p] = make_float4(x, y, z, x2);
  }
  __syncthreads();
  const float qx = pts[q * 3 + 0], qy = pts[q * 3 + 1], qz = pts[q * 3 + 2];
  const float q2 = __fadd_rn(
      __fadd_rn(__fmul_rn(qx, qx), __fmul_rn(qy, qy)), __fmul_rn(qz, qz));
  TOPK_DECL;
#pragma unroll 4
  for (int p = 0; p < SLICE_LEN; ++p) {
    float4 pj = sp[p];
    float dot = __fmaf_rn(qz, pj.z, __fmaf_rn(qy, pj.y, __fmul_rn(qx, pj.x)));
    float t1 = __fadd_rn(q2, pj.w);
    float d = __fadd_rn(t1, __fmul_rn(-2.0f, dot));
    TOPK_INSERT(d, jbase + p);
  }
  part_d[(blockIdx.y * KNN + 0) * NPTS + q] = d0;
  part_d[(blockIdx.y * KNN + 1) * NPTS + q] = d1;
  part_d[(blockIdx.y * KNN + 2) * NPTS + q] = d2;
  part_d[(blockIdx.y * KNN + 3) * NPTS + q] = d3;
  part_d[(blockIdx.y * KNN + 4) * NPTS + q] = d4;
  part_d[(blockIdx.y * KNN + 5) * NPTS + q] = d5;
  part_d[(blockIdx.y * KNN + 6) * NPTS + q] = d6;
  part_d[(blockIdx.y * KNN + 7) * NPTS + q] = d7;
  part_i[(blockIdx.y * KNN + 0) * NPTS + q] = i0;
  part_i[(blockIdx.y * KNN + 1) * NPTS + q] = i1;
  part_i[(blockIdx.y * KNN + 2) * NPTS + q] = i2;
  part_i[(blockIdx.y * KNN + 3) * NPTS + q] = i3;
  part_i[(blockIdx.y * KNN + 4) * NPTS + q] = i4;
  part_i[(blockIdx.y * KNN + 5) * NPTS + q] = i5;
  part_i[(blockIdx.y * KNN + 6) * NPTS + q] = i6;
  part_i[(blockIdx.y * KNN + 7) * NPTS + q] = i7;
}

// KNN stage 2: merge 16 slices x 8 candidates per query. Slices visited in
// ascending-j order; strict < keeps lower index on ties (matches top_k).
__global__ __launch_bounds__(64) void knn_merge_kernel(
    const float* __restrict__ part_d, const int* __restrict__ part_i,
    int* __restrict__ nbr) {
  const int q = blockIdx.x * 64 + threadIdx.x;
  TOPK_DECL;
  for (int sl = 0; sl < NSLICE; ++sl) {
    float cd[KNN];
    int cidx[KNN];
#pragma unroll
    for (int e = 0; e < KNN; ++e) {
      cd[e] = part_d[(sl * KNN + e) * NPTS + q];
      cidx[e] = part_i[(sl * KNN + e) * NPTS + q];
    }
#pragma unroll
    for (int e = 0; e < KNN; ++e) TOPK_INSERT(cd[e], cidx[e]);
  }
  nbr[q * KNN + 0] = i0;
  nbr[q * KNN + 1] = i1;
  nbr[q * KNN + 2] = i2;
  nbr[q * KNN + 3] = i3;
  nbr[q * KNN + 4] = i4;
  nbr[q * KNN + 5] = i5;
  nbr[q * KNN + 6] = i6;
  nbr[q * KNN + 7] = i7;
}

// Per-edge first layer of EdgeConv1: H1[edge][m] = relu(e @ W1 + b1), m<64.
__global__ __launch_bounds__(256) void h1_edges_kernel(
    const float* __restrict__ pts, const int* __restrict__ nbr,
    const float* __restrict__ W1, const float* __restrict__ b1,
    float* __restrict__ H1) {
  const int id = blockIdx.x * 256 + threadIdx.x;  // 65536 * 16
  const int te = id >> 4, mq = id & 15;
  const int i = te >> 3;
  const int j = nbr[te];
  const float xi0 = pts[i * 3], xi1 = pts[i * 3 + 1], xi2 = pts[i * 3 + 2];
  const float d0 = pts[j * 3] - xi0, d1 = pts[j * 3 + 1] - xi1,
              d2 = pts[j * 3 + 2] - xi2;
  const int m = mq * 4;
  float4 o;
  float* oa = (float*)&o;
#pragma unroll
  for (int d = 0; d < 4; ++d) {
    int c = m + d;
    float v = b1[c];
    v += xi0 * W1[0 * 64 + c] + xi1 * W1[1 * 64 + c] + xi2 * W1[2 * 64 + c];
    v += d0 * W1[3 * 64 + c] + d1 * W1[4 * 64 + c] + d2 * W1[5 * 64 + c];
    oa[d] = fmaxf(v, 0.0f);
  }
  *(float4*)&H1[(size_t)te * 64 + m] = o;
}

// Build Wcat (128 x 256): cols 0..127 = W3[0:128,:], cols 128..255 = W3[128:256,:].
__global__ __launch_bounds__(256) void build_wcat_kernel(
    const float* __restrict__ W3, float* __restrict__ Wcat) {
  const int id = blockIdx.x * 256 + threadIdx.x;  // 32768
  const int k = id >> 8, c = id & 255;
  Wcat[id] = (c < 128) ? W3[k * 128 + c] : W3[(128 + k) * 128 + (c - 128)];
}

// Per-edge first layer of EdgeConv2: H2[edge][c] = relu(A_i + C_j - C_i).
__global__ __launch_bounds__(256) void h2_edges_kernel(
    const float* __restrict__ AC, const int* __restrict__ nbr,
    float* __restrict__ H2) {
  const int id = blockIdx.x * 256 + threadIdx.x;  // 65536 * 32
  const int te = id >> 5, cq = id & 31;
  const int i = te >> 3;
  const int j = nbr[te];
  const int c = cq * 4;
  float4 a = *(const float4*)&AC[(size_t)i * 256 + c];
  float4 ci = *(const float4*)&AC[(size_t)i * 256 + 128 + c];
  float4 cj = *(const float4*)&AC[(size_t)j * 256 + 128 + c];
  float4 h;
  h.x = fmaxf(a.x + cj.x - ci.x, 0.0f);
  h.y = fmaxf(a.y + cj.y - ci.y, 0.0f);
  h.z = fmaxf(a.z + cj.z - ci.z, 0.0f);
  h.w = fmaxf(a.w + cj.w - ci.w, 0.0f);
  *(float4*)&H2[(size_t)te * 128 + c] = h;
}

// ---------------------------------------------------------------------------
// Tiled fp32 GEMM: out = op(A[M x K] @ B[K x Nglob] + bias).
// 64x64 tile, K-panel 64 in LDS, 4x4 register micro-tile per thread.
// ---------------------------------------------------------------------------
template <bool SEGMAX, bool RELU>
__global__ __launch_bounds__(256) void gemm_kernel(
    const float* __restrict__ A, const float* __restrict__ B,
    const float* __restrict__ bias, int bias_limit, float* __restrict__ out,
    int K, int Nglob) {
  __shared__ float As[64][64];  // As[k][row]
  __shared__ float Bs[64][64];  // Bs[k][col]
  const int t = threadIdx.x;
  const int tx = t & 15, ty = t >> 4;
  const int rowBase = blockIdx.y * 64;
  const int colBase = blockIdx.x * 64;
  const float4* A4 = (const float4*)A;
  float acc[4][4] = {};

  for (int k0 = 0; k0 < K; k0 += 64) {
#pragma unroll
    for (int it = 0; it < 4; ++it) {
      int idx = it * 256 + t;
      int row = idx & 63, kq = idx >> 6;
      float4 av = A4[(size_t)(rowBase + row) * (K >> 2) + (k0 >> 2) + kq];
      As[kq * 4 + 0][row] = av.x;
      As[kq * 4 + 1][row] = av.y;
      As[kq * 4 + 2][row] = av.z;
      As[kq * 4 + 3][row] = av.w;
    }
#pragma unroll
    for (int it = 0; it < 4; ++it) {
      int idx = it * 256 + t;
      int cq = idx & 15, kr = idx >> 4;
      float4 bv = *(const float4*)&B[(size_t)(k0 + kr) * Nglob + colBase + cq * 4];
      *(float4*)&Bs[kr][cq * 4] = bv;
    }
    __syncthreads();
#pragma unroll 8
    for (int k = 0; k < 64; ++k) {
      float4 a = *(const float4*)&As[k][ty * 4];
      float4 b = *(const float4*)&Bs[k][tx * 4];
      const float ar[4] = {a.x, a.y, a.z, a.w};
      const float br[4] = {b.x, b.y, b.z, b.w};
#pragma unroll
      for (int i = 0; i < 4; ++i)
#pragma unroll
        for (int jj = 0; jj < 4; ++jj)
          acc[i][jj] = fmaf(ar[i], br[jj], acc[i][jj]);
    }
    __syncthreads();
  }

  if (SEGMAX) {
    float* Mx = &As[0][0];
#pragma unroll
    for (int jj = 0; jj < 4; ++jj) {
      float m = fmaxf(fmaxf(acc[0][jj], acc[1][jj]),
                      fmaxf(acc[2][jj], acc[3][jj]));
      Mx[ty * 64 + tx * 4 + jj] = m;
    }
    __syncthreads();
    if (t < 128) {
      int p = t >> 4, cq = t & 15;
      int c = cq * 4;
      float4 o;
      float* oa = (float*)&o;
#pragma unroll
      for (int jj = 0; jj < 4; ++jj) {
        float v = fmaxf(Mx[(2 * p) * 64 + c + jj], Mx[(2 * p + 1) * 64 + c + jj]);
        int cg = colBase + c + jj;
        if (cg < bias_limit) v += bias[cg];
        if (RELU) v = fmaxf(v, 0.0f);
        oa[jj] = v;
      }
      *(float4*)&out[(size_t)(blockIdx.y * 8 + p) * Nglob + colBase + c] = o;
    }
  } else {
#pragma unroll
    for (int i = 0; i < 4; ++i) {
      float4 o;
      float* oa = (float*)&o;
#pragma unroll
      for (int jj = 0; jj < 4; ++jj) {
        float v = acc[i][jj];
        int cg = colBase + tx * 4 + jj;
        if (cg < bias_limit) v += bias[cg];
        oa[jj] = v;
      }
      *(float4*)&out[(size_t)(rowBase + ty * 4 + i) * Nglob + colBase + tx * 4] = o;
    }
  }
}

extern "C" void kernel_launch(void* const* d_in, const int* in_sizes, int n_in,
                              void* d_out, int out_size, void* d_ws,
                              size_t ws_size, hipStream_t stream) {
  const float* pts = (const float*)d_in[0];
  const float* W1 = (const float*)d_in[1];
  const float* b1 = (const float*)d_in[2];
  const float* W2 = (const float*)d_in[3];
  const float* b2 = (const float*)d_in[4];
  const float* W3 = (const float*)d_in[5];
  const float* b3 = (const float*)d_in[6];
  const float* W4 = (const float*)d_in[7];
  const float* b4 = (const float*)d_in[8];
  float* out = (float*)d_out;

  float* w = (float*)d_ws;
  float* part_d = w;                               // 1048576 f
  int* part_i = (int*)(w + 1048576);               // 1048576 i
  int* nbr = (int*)(w + 2097152);                  // 65536 i
  float* H1 = w + 2162688;                         // 4194304 f
  float* y = w + 6356992;                          // 1048576 f
  float* Wcat = w + 7405568;                       // 32768 f
  float* AC = w + 7438336;                         // 2097152 f
  float* H2 = w + 9535488;                         // 8388608 f

  // 1. KNN
  knn_partial_kernel<<<dim3(32, NSLICE), 256, 0, stream>>>(pts, part_d, part_i);
  knn_merge_kernel<<<128, 64, 0, stream>>>(part_d, part_i, nbr);

  // 2. EdgeConv1
  h1_edges_kernel<<<4096, 256, 0, stream>>>(pts, nbr, W1, b1, H1);
  gemm_kernel<true, true><<<dim3(2, 1024), 256, 0, stream>>>(
      H1, W2, b2, 128, y, 64, 128);

  // 3. EdgeConv2
  build_wcat_kernel<<<128, 256, 0, stream>>>(W3, Wcat);
  gemm_kernel<false, false><<<dim3(4, 128), 256, 0, stream>>>(
      y, Wcat, b3, 128, AC, 128, 256);
  h2_edges_kernel<<<8192, 256, 0, stream>>>(AC, nbr, H2);
  gemm_kernel<true, false><<<dim3(4, 1024), 256, 0, stream>>>(
      H2, W4, b4, 256, out, 128, 256);
}

// Round 3
// 264.665 us; speedup vs baseline: 1.7710x; 1.0423x over previous
//
#include <hip/hip_runtime.h>

#define NPTS 8192
#define NSLICE 16
#define SLICE_LEN (NPTS / NSLICE)
#define KNN 8

// ---------------------------------------------------------------------------
// Branch-free insert of (dist,idx) into ascending sorted regs d0..d7/i0..i7,
// hand-scheduled: 8 v_cmp + 30 v_cndmask, alternating vcc and one SGPR pair.
// Each compare c_s = (d < d_s) reads the OLD d_s (issued before stage s
// overwrites it). Strict < keeps earlier (lower-index) candidate on ties,
// matching jax.lax.top_k.
// ---------------------------------------------------------------------------
#define TOPK_INSERT_ASM(dist, idxv)                                           \
  {                                                                           \
    const float _d = (dist);                                                  \
    const int _ix = (idxv);                                                   \
    float _tf;                                                                \
    int _ti;                                                                  \
    unsigned long long _m;                                                    \
    asm("v_cmp_lt_f32 vcc, %[vd], %[D7]\n\t"                                  \
        "v_cmp_lt_f32 %[M], %[vd], %[D6]\n\t"                                 \
        "v_cndmask_b32 %[TF], %[vd], %[D6], %[M]\n\t"                         \
        "v_cndmask_b32 %[D7], %[D7], %[TF], vcc\n\t"                          \
        "v_cndmask_b32 %[TI], %[vi], %[I6], %[M]\n\t"                         \
        "v_cndmask_b32 %[I7], %[I7], %[TI], vcc\n\t"                          \
        "v_cmp_lt_f32 vcc, %[vd], %[D5]\n\t"                                  \
        "v_cndmask_b32 %[TF], %[vd], %[D5], vcc\n\t"                          \
        "v_cndmask_b32 %[D6], %[D6], %[TF], %[M]\n\t"                         \
        "v_cndmask_b32 %[TI], %[vi], %[I5], vcc\n\t"                          \
        "v_cndmask_b32 %[I6], %[I6], %[TI], %[M]\n\t"                         \
        "v_cmp_lt_f32 %[M], %[vd], %[D4]\n\t"                                 \
        "v_cndmask_b32 %[TF], %[vd], %[D4], %[M]\n\t"                         \
        "v_cndmask_b32 %[D5], %[D5], %[TF], vcc\n\t"                          \
        "v_cndmask_b32 %[TI], %[vi], %[I4], %[M]\n\t"                         \
        "v_cndmask_b32 %[I5], %[I5], %[TI], vcc\n\t"                          \
        "v_cmp_lt_f32 vcc, %[vd], %[D3]\n\t"                                  \
        "v_cndmask_b32 %[TF], %[vd], %[D3], vcc\n\t"                          \
        "v_cndmask_b32 %[D4], %[D4], %[TF], %[M]\n\t"                         \
        "v_cndmask_b32 %[TI], %[vi], %[I3], vcc\n\t"                          \
        "v_cndmask_b32 %[I4], %[I4], %[TI], %[M]\n\t"                         \
        "v_cmp_lt_f32 %[M], %[vd], %[D2]\n\t"                                 \
        "v_cndmask_b32 %[TF], %[vd], %[D2], %[M]\n\t"                         \
        "v_cndmask_b32 %[D3], %[D3], %[TF], vcc\n\t"                          \
        "v_cndmask_b32 %[TI], %[vi], %[I2], %[M]\n\t"                         \
        "v_cndmask_b32 %[I3], %[I3], %[TI], vcc\n\t"                          \
        "v_cmp_lt_f32 vcc, %[vd], %[D1]\n\t"                                  \
        "v_cndmask_b32 %[TF], %[vd], %[D1], vcc\n\t"                          \
        "v_cndmask_b32 %[D2], %[D2], %[TF], %[M]\n\t"                         \
        "v_cndmask_b32 %[TI], %[vi], %[I1], vcc\n\t"                          \
        "v_cndmask_b32 %[I2], %[I2], %[TI], %[M]\n\t"                         \
        "v_cmp_lt_f32 %[M], %[vd], %[D0]\n\t"                                 \
        "v_cndmask_b32 %[TF], %[vd], %[D0], %[M]\n\t"                         \
        "v_cndmask_b32 %[D1], %[D1], %[TF], vcc\n\t"                          \
        "v_cndmask_b32 %[TI], %[vi], %[I0], %[M]\n\t"                         \
        "v_cndmask_b32 %[I1], %[I1], %[TI], vcc\n\t"                          \
        "v_cndmask_b32 %[D0], %[D0], %[vd], %[M]\n\t"                         \
        "v_cndmask_b32 %[I0], %[I0], %[vi], %[M]"                             \
        : [D0] "+v"(d0), [D1] "+v"(d1), [D2] "+v"(d2), [D3] "+v"(d3),         \
          [D4] "+v"(d4), [D5] "+v"(d5), [D6] "+v"(d6), [D7] "+v"(d7),         \
          [I0] "+v"(i0), [I1] "+v"(i1), [I2] "+v"(i2), [I3] "+v"(i3),         \
          [I4] "+v"(i4), [I5] "+v"(i5), [I6] "+v"(i6), [I7] "+v"(i7),         \
          [TF] "=&v"(_tf), [TI] "=&v"(_ti), [M] "=&s"(_m)                     \
        : [vd] "v"(_d), [vi] "v"(_ix)                                         \
        : "vcc");                                                             \
  }

// C fallback insert (used in the tiny merge kernel).
#define TOPK_INSERT(dist, idx)                                              \
  {                                                                         \
    const float _d = (dist);                                                \
    const int _ix = (idx);                                                  \
    const bool c0 = _d < d0, c1 = _d < d1, c2 = _d < d2, c3 = _d < d3;      \
    const bool c4 = _d < d4, c5 = _d < d5, c6 = _d < d6, c7 = _d < d7;      \
    d7 = c7 ? (c6 ? d6 : _d) : d7; i7 = c7 ? (c6 ? i6 : _ix) : i7;          \
    d6 = c6 ? (c5 ? d5 : _d) : d6; i6 = c6 ? (c5 ? i5 : _ix) : i6;          \
    d5 = c5 ? (c4 ? d4 : _d) : d5; i5 = c5 ? (c4 ? i4 : _ix) : i5;          \
    d4 = c4 ? (c3 ? d3 : _d) : d4; i4 = c4 ? (c3 ? i3 : _ix) : i4;          \
    d3 = c3 ? (c2 ? d2 : _d) : d3; i3 = c3 ? (c2 ? i2 : _ix) : i3;          \
    d2 = c2 ? (c1 ? d1 : _d) : d2; i2 = c2 ? (c1 ? i1 : _ix) : i2;          \
    d1 = c1 ? (c0 ? d0 : _d) : d1; i1 = c1 ? (c0 ? i0 : _ix) : i1;          \
    d0 = c0 ? _d : d0;             i0 = c0 ? _ix : i0;                      \
  }

#define TOPK_DECL                                                           \
  float d0 = 3.4e38f, d1 = 3.4e38f, d2 = 3.4e38f, d3 = 3.4e38f,            \
        d4 = 3.4e38f, d5 = 3.4e38f, d6 = 3.4e38f, d7 = 3.4e38f;            \
  int i0 = 0, i1 = 0, i2 = 0, i3 = 0, i4 = 0, i5 = 0, i6 = 0, i7 = 0;

// ---------------------------------------------------------------------------
// KNN stage 1: 256 queries x one slice of 512 candidates per block.
// Distance replicates numpy rounding:
//   x2 = ((x*x + y*y) + z*z); dot = fma-chain; d = (x2i + x2j) + (-2*dot)
// ---------------------------------------------------------------------------
__global__ __launch_bounds__(256) void knn_partial_kernel(
    const float* __restrict__ pts, float* __restrict__ part_d,
    int* __restrict__ part_i) {
  __shared__ float4 sp[SLICE_LEN];
  const int t = threadIdx.x;
  const int q = blockIdx.x * 256 + t;
  const int jbase = blockIdx.y * SLICE_LEN;
  for (int p = t; p < SLICE_LEN; p += 256) {
    float x = pts[(jbase + p) * 3 + 0];
    float y = pts[(jbase + p) * 3 + 1];
    float z = pts[(jbase + p) * 3 + 2];
    float x2 = __fadd_rn(__fadd_rn(__fmul_rn(x, x), __fmul_rn(y, y)),
                         __fmul_rn(z, z));
    sp[p] = make_float4(x, y, z, x2);
  }
  __syncthreads();
  const float qx = pts[q * 3 + 0], qy = pts[q * 3 + 1], qz = pts[q * 3 + 2];
  const float q2 = __fadd_rn(
      __fadd_rn(__fmul_rn(qx, qx), __fmul_rn(qy, qy)), __fmul_rn(qz, qz));
  TOPK_DECL;
#pragma unroll 4
  for (int p = 0; p < SLICE_LEN; ++p) {
    float4 pj = sp[p];
    float dot = __fmaf_rn(qz, pj.z, __fmaf_rn(qy, pj.y, __fmul_rn(qx, pj.x)));
    float t1 = __fadd_rn(q2, pj.w);
    float d = __fadd_rn(t1, __fmul_rn(-2.0f, dot));
    TOPK_INSERT_ASM(d, jbase + p);
  }
  part_d[(blockIdx.y * KNN + 0) * NPTS + q] = d0;
  part_d[(blockIdx.y * KNN + 1) * NPTS + q] = d1;
  part_d[(blockIdx.y * KNN + 2) * NPTS + q] = d2;
  part_d[(blockIdx.y * KNN + 3) * NPTS + q] = d3;
  part_d[(blockIdx.y * KNN + 4) * NPTS + q] = d4;
  part_d[(blockIdx.y * KNN + 5) * NPTS + q] = d5;
  part_d[(blockIdx.y * KNN + 6) * NPTS + q] = d6;
  part_d[(blockIdx.y * KNN + 7) * NPTS + q] = d7;
  part_i[(blockIdx.y * KNN + 0) * NPTS + q] = i0;
  part_i[(blockIdx.y * KNN + 1) * NPTS + q] = i1;
  part_i[(blockIdx.y * KNN + 2) * NPTS + q] = i2;
  part_i[(blockIdx.y * KNN + 3) * NPTS + q] = i3;
  part_i[(blockIdx.y * KNN + 4) * NPTS + q] = i4;
  part_i[(blockIdx.y * KNN + 5) * NPTS + q] = i5;
  part_i[(blockIdx.y * KNN + 6) * NPTS + q] = i6;
  part_i[(blockIdx.y * KNN + 7) * NPTS + q] = i7;
}

// KNN stage 2: merge 16 slices x 8 candidates per query (ascending-j order).
__global__ __launch_bounds__(64) void knn_merge_kernel(
    const float* __restrict__ part_d, const int* __restrict__ part_i,
    int* __restrict__ nbr) {
  const int q = blockIdx.x * 64 + threadIdx.x;
  TOPK_DECL;
  for (int sl = 0; sl < NSLICE; ++sl) {
    float cd[KNN];
    int cidx[KNN];
#pragma unroll
    for (int e = 0; e < KNN; ++e) {
      cd[e] = part_d[(sl * KNN + e) * NPTS + q];
      cidx[e] = part_i[(sl * KNN + e) * NPTS + q];
    }
#pragma unroll
    for (int e = 0; e < KNN; ++e) TOPK_INSERT(cd[e], cidx[e]);
  }
  nbr[q * KNN + 0] = i0;
  nbr[q * KNN + 1] = i1;
  nbr[q * KNN + 2] = i2;
  nbr[q * KNN + 3] = i3;
  nbr[q * KNN + 4] = i4;
  nbr[q * KNN + 5] = i5;
  nbr[q * KNN + 6] = i6;
  nbr[q * KNN + 7] = i7;
}

// ---------------------------------------------------------------------------
// Fused EdgeConv1: per block, compute the 64-edge x 64-channel H1 tile
// in-register/LDS (from pts, nbr, W1, b1), then GEMM with W2 (K=64),
// segmented max over 8 edges/point, +b2, relu -> y (8192 x 128).
// grid: dim3(2, 1024)
// ---------------------------------------------------------------------------
__global__ __launch_bounds__(256) void gemm1_fused_kernel(
    const float* __restrict__ pts, const int* __restrict__ nbr,
    const float* __restrict__ W1, const float* __restrict__ b1,
    const float* __restrict__ W2, const float* __restrict__ b2,
    float* __restrict__ y) {
  __shared__ float es[64][6];
  __shared__ float W1s[6][64];
  __shared__ float b1s[64];
  __shared__ float As[64][64];  // As[k][edge]
  __shared__ float Bs[64][64];  // Bs[k][col]
  const int t = threadIdx.x;
  const int rowBase = blockIdx.y * 64;  // edge base
  const int colBase = blockIdx.x * 64;

  for (int idx = t; idx < 384; idx += 256) W1s[idx >> 6][idx & 63] = W1[idx];
  if (t < 64) b1s[t] = b1[t];
  {
    int cq = t & 15, kr = t >> 4;  // kr 0..15
#pragma unroll
    for (int it = 0; it < 4; ++it) {
      int k = it * 16 + kr;
      *(float4*)&Bs[k][cq * 4] =
          *(const float4*)&W2[(size_t)k * 128 + colBase + cq * 4];
    }
  }
  if (t < 64) {
    int e = rowBase + t;
    int i = e >> 3;
    int j = nbr[e];
    float xi0 = pts[i * 3], xi1 = pts[i * 3 + 1], xi2 = pts[i * 3 + 2];
    es[t][0] = xi0;
    es[t][1] = xi1;
    es[t][2] = xi2;
    es[t][3] = pts[j * 3] - xi0;
    es[t][4] = pts[j * 3 + 1] - xi1;
    es[t][5] = pts[j * 3 + 2] - xi2;
  }
  __syncthreads();

  {
    const int e = t & 63, k0 = (t >> 6) * 16;
    const float f0 = es[e][0], f1 = es[e][1], f2 = es[e][2];
    const float f3 = es[e][3], f4 = es[e][4], f5 = es[e][5];
#pragma unroll
    for (int k = 0; k < 16; ++k) {
      int c = k0 + k;
      float v = b1s[c];
      v = fmaf(f0, W1s[0][c], v);
      v = fmaf(f1, W1s[1][c], v);
      v = fmaf(f2, W1s[2][c], v);
      v = fmaf(f3, W1s[3][c], v);
      v = fmaf(f4, W1s[4][c], v);
      v = fmaf(f5, W1s[5][c], v);
      As[c][e] = fmaxf(v, 0.0f);
    }
  }
  __syncthreads();

  const int tx = t & 15, ty = t >> 4;
  float acc[4][4] = {};
#pragma unroll 8
  for (int k = 0; k < 64; ++k) {
    float4 a = *(const float4*)&As[k][ty * 4];
    float4 b = *(const float4*)&Bs[k][tx * 4];
    const float ar[4] = {a.x, a.y, a.z, a.w};
    const float br[4] = {b.x, b.y, b.z, b.w};
#pragma unroll
    for (int i = 0; i < 4; ++i)
#pragma unroll
      for (int jj = 0; jj < 4; ++jj)
        acc[i][jj] = fmaf(ar[i], br[jj], acc[i][jj]);
  }
  __syncthreads();

  float* Mx = &As[0][0];
#pragma unroll
  for (int jj = 0; jj < 4; ++jj) {
    float m =
        fmaxf(fmaxf(acc[0][jj], acc[1][jj]), fmaxf(acc[2][jj], acc[3][jj]));
    Mx[ty * 64 + tx * 4 + jj] = m;
  }
  __syncthreads();
  if (t < 128) {
    int p = t >> 4, cq = t & 15;
    int c = cq * 4;
    float4 o;
    float* oa = (float*)&o;
#pragma unroll
    for (int jj = 0; jj < 4; ++jj) {
      float v = fmaxf(Mx[(2 * p) * 64 + c + jj], Mx[(2 * p + 1) * 64 + c + jj]);
      v += b2[colBase + c + jj];
      oa[jj] = fmaxf(v, 0.0f);
    }
    *(float4*)&y[(size_t)(blockIdx.y * 8 + p) * 128 + colBase + c] = o;
  }
}

// Build Wcat (128 x 256): cols 0..127 = W3[0:128,:], cols 128..255 = W3[128:256,:].
__global__ __launch_bounds__(256) void build_wcat_kernel(
    const float* __restrict__ W3, float* __restrict__ Wcat) {
  const int id = blockIdx.x * 256 + threadIdx.x;  // 32768
  const int k = id >> 8, c = id & 255;
  Wcat[id] = (c < 128) ? W3[k * 128 + c] : W3[(128 + k) * 128 + (c - 128)];
}

// Per-edge first layer of EdgeConv2: H2[edge][c] = relu(A_i + C_j - C_i).
__global__ __launch_bounds__(256) void h2_edges_kernel(
    const float* __restrict__ AC, const int* __restrict__ nbr,
    float* __restrict__ H2) {
  const int id = blockIdx.x * 256 + threadIdx.x;  // 65536 * 32
  const int te = id >> 5, cq = id & 31;
  const int i = te >> 3;
  const int j = nbr[te];
  const int c = cq * 4;
  float4 a = *(const float4*)&AC[(size_t)i * 256 + c];
  float4 ci = *(const float4*)&AC[(size_t)i * 256 + 128 + c];
  float4 cj = *(const float4*)&AC[(size_t)j * 256 + 128 + c];
  float4 h;
  h.x = fmaxf(a.x + cj.x - ci.x, 0.0f);
  h.y = fmaxf(a.y + cj.y - ci.y, 0.0f);
  h.z = fmaxf(a.z + cj.z - ci.z, 0.0f);
  h.w = fmaxf(a.w + cj.w - ci.w, 0.0f);
  *(float4*)&H2[(size_t)te * 128 + c] = h;
}

// ---------------------------------------------------------------------------
// Tiled fp32 GEMM (as R2): 64x64 tile, K-panel 64 LDS, 4x4 micro-tile.
// ---------------------------------------------------------------------------
template <bool SEGMAX, bool RELU>
__global__ __launch_bounds__(256) void gemm_kernel(
    const float* __restrict__ A, const float* __restrict__ B,
    const float* __restrict__ bias, int bias_limit, float* __restrict__ out,
    int K, int Nglob) {
  __shared__ float As[64][64];
  __shared__ float Bs[64][64];
  const int t = threadIdx.x;
  const int tx = t & 15, ty = t >> 4;
  const int rowBase = blockIdx.y * 64;
  const int colBase = blockIdx.x * 64;
  const float4* A4 = (const float4*)A;
  float acc[4][4] = {};

  for (int k0 = 0; k0 < K; k0 += 64) {
#pragma unroll
    for (int it = 0; it < 4; ++it) {
      int idx = it * 256 + t;
      int row = idx & 63, kq = idx >> 6;
      float4 av = A4[(size_t)(rowBase + row) * (K >> 2) + (k0 >> 2) + kq];
      As[kq * 4 + 0][row] = av.x;
      As[kq * 4 + 1][row] = av.y;
      As[kq * 4 + 2][row] = av.z;
      As[kq * 4 + 3][row] = av.w;
    }
#pragma unroll
    for (int it = 0; it < 4; ++it) {
      int idx = it * 256 + t;
      int cq = idx & 15, kr = idx >> 4;
      float4 bv = *(const float4*)&B[(size_t)(k0 + kr) * Nglob + colBase + cq * 4];
      *(float4*)&Bs[kr][cq * 4] = bv;
    }
    __syncthreads();
#pragma unroll 8
    for (int k = 0; k < 64; ++k) {
      float4 a = *(const float4*)&As[k][ty * 4];
      float4 b = *(const float4*)&Bs[k][tx * 4];
      const float ar[4] = {a.x, a.y, a.z, a.w};
      const float br[4] = {b.x, b.y, b.z, b.w};
#pragma unroll
      for (int i = 0; i < 4; ++i)
#pragma unroll
        for (int jj = 0; jj < 4; ++jj)
          acc[i][jj] = fmaf(ar[i], br[jj], acc[i][jj]);
    }
    __syncthreads();
  }

  if (SEGMAX) {
    float* Mx = &As[0][0];
#pragma unroll
    for (int jj = 0; jj < 4; ++jj) {
      float m = fmaxf(fmaxf(acc[0][jj], acc[1][jj]),
                      fmaxf(acc[2][jj], acc[3][jj]));
      Mx[ty * 64 + tx * 4 + jj] = m;
    }
    __syncthreads();
    if (t < 128) {
      int p = t >> 4, cq = t & 15;
      int c = cq * 4;
      float4 o;
      float* oa = (float*)&o;
#pragma unroll
      for (int jj = 0; jj < 4; ++jj) {
        float v = fmaxf(Mx[(2 * p) * 64 + c + jj], Mx[(2 * p + 1) * 64 + c + jj]);
        int cg = colBase + c + jj;
        if (cg < bias_limit) v += bias[cg];
        if (RELU) v = fmaxf(v, 0.0f);
        oa[jj] = v;
      }
      *(float4*)&out[(size_t)(blockIdx.y * 8 + p) * Nglob + colBase + c] = o;
    }
  } else {
#pragma unroll
    for (int i = 0; i < 4; ++i) {
      float4 o;
      float* oa = (float*)&o;
#pragma unroll
      for (int jj = 0; jj < 4; ++jj) {
        float v = acc[i][jj];
        int cg = colBase + tx * 4 + jj;
        if (cg < bias_limit) v += bias[cg];
        oa[jj] = v;
      }
      *(float4*)&out[(size_t)(rowBase + ty * 4 + i) * Nglob + colBase + tx * 4] = o;
    }
  }
}

extern "C" void kernel_launch(void* const* d_in, const int* in_sizes, int n_in,
                              void* d_out, int out_size, void* d_ws,
                              size_t ws_size, hipStream_t stream) {
  const float* pts = (const float*)d_in[0];
  const float* W1 = (const float*)d_in[1];
  const float* b1 = (const float*)d_in[2];
  const float* W2 = (const float*)d_in[3];
  const float* b2 = (const float*)d_in[4];
  const float* W3 = (const float*)d_in[5];
  const float* b3 = (const float*)d_in[6];
  const float* W4 = (const float*)d_in[7];
  const float* b4 = (const float*)d_in[8];
  float* out = (float*)d_out;

  float* w = (float*)d_ws;
  float* part_d = w;                               // 1048576 f
  int* part_i = (int*)(w + 1048576);               // 1048576 i
  int* nbr = (int*)(w + 2097152);                  // 65536 i
  float* y = w + 6356992;                          // 1048576 f
  float* Wcat = w + 7405568;                       // 32768 f
  float* AC = w + 7438336;                         // 2097152 f
  float* H2 = w + 9535488;                         // 8388608 f

  // 1. KNN
  knn_partial_kernel<<<dim3(32, NSLICE), 256, 0, stream>>>(pts, part_d, part_i);
  knn_merge_kernel<<<128, 64, 0, stream>>>(part_d, part_i, nbr);

  // 2. EdgeConv1 (fused H1 + GEMM + max8 + b2 + relu)
  gemm1_fused_kernel<<<dim3(2, 1024), 256, 0, stream>>>(pts, nbr, W1, b1, W2,
                                                        b2, y);

  // 3. EdgeConv2
  build_wcat_kernel<<<128, 256, 0, stream>>>(W3, Wcat);
  gemm_kernel<false, false><<<dim3(4, 128), 256, 0, stream>>>(
      y, Wcat, b3, 128, AC, 128, 256);
  h2_edges_kernel<<<8192, 256, 0, stream>>>(AC, nbr, H2);
  gemm_kernel<true, false><<<dim3(4, 1024), 256, 0, stream>>>(
      H2, W4, b4, 256, out, 128, 256);
}